// Round 4
// baseline (242.828 us; speedup 1.0000x reference)
//
#include <hip/hip_runtime.h>
#include <math.h>

#define T_SEQ 34
#define NTOK 14
#define NE (T_SEQ * NTOK) // 476
#define ROWS 30           // rows per block; 17 pairs x 30 rows = 510 threads
#define BLK 512
#define NEL (ROWS * T_SEQ) // 1020 elements per block
#define AVS (ROWS + 1)     // Av row stride (31)
#define TTS (ROWS + 1)     // toksT row stride (31)

__global__ __launch_bounds__(BLK) void micro_fused_kernel(
    const int* __restrict__ idx,
    const float* __restrict__ tok_emb,
    const float* __restrict__ s_amp, const float* __restrict__ s_phase,
    const float* __restrict__ s_slope, const float* __restrict__ s_offset,
    const float* __restrict__ pc_slope, const float* __restrict__ pc_int,
    const float* __restrict__ z_hi, const float* __restrict__ spec,
    const float* __restrict__ q_w, const float* __restrict__ v_w,
    const float* __restrict__ out_A, const float* __restrict__ out_B,
    const float* __restrict__ q_phase,
    const float* __restrict__ ln1_w, const float* __restrict__ ln2_w,
    const float* __restrict__ lnf_w,
    const float* __restrict__ fc1_w, const float* __restrict__ fc1_b,
    const float* __restrict__ fc2_w, const float* __restrict__ fc2_b,
    const float* __restrict__ head_w,
    float* __restrict__ out, int N)
{
    // per-(t,tok) tables
    __shared__ float4 C3[NE];      // q_w^T @ q_rot * invsqrt(5) * log2(e)
    __shared__ float4 Rt[NE];      // (rn, h0, h1, 0) per (s,tok)
    __shared__ float4 PW[T_SEQ];   // (px*w2, py*w3, pz*w4, 0) per s (wave-uniform)
    __shared__ float2 Av[T_SEQ * AVS];
    __shared__ int    toksT[T_SEQ * TTS];
    alignas(16) __shared__ float PosT[T_SEQ * 3];
    alignas(16) __shared__ float TE[NTOK * 2];
    alignas(16) __shared__ float PMs[12];
    alignas(16) __shared__ float WsT[NTOK * 8];
    alignas(16) __shared__ float ln2s[8], lnfs[8], fc1ws[12], fc2ws[12], fc2bs[8];
    __shared__ float fc1bs[2];

    const int tid = threadIdx.x;
    const int b0 = blockIdx.x * ROWS;
    const int elemBase = b0 * T_SEQ;

    // ---- stage tokens (coalesced read, transposed store) ----
    for (int i = tid; i < NEL; i += BLK) {
        int g = elemBase + i;
        int v = (g < N) ? idx[g] : 0;
        int r = i / T_SEQ, s = i - r * T_SEQ;
        toksT[s * TTS + r] = v;
    }

    // ---- build per-(t,tok) tables ----
    if (tid < NE) {
        const float amp = s_amp[0], ph = s_phase[0], slp = s_slope[0], off = s_offset[0];
        const float pcs = pc_slope[0], pci = pc_int[0];
        const float cph = cosf(q_phase[0]), sph = sinf(q_phase[0]);
        const float cscale = 0.44721359549995793f * 1.4426950408889634f; // 1/sqrt(5)*log2e
        const int e = tid;
        const int t = e / NTOK, tk = e - t * NTOK;
        float px, py, pz;
        if (t == 33)      { px = 0.f;     py = 0.f;     pz = 0.f; }
        else if (t == 32) { px = z_hi[0]; py = z_hi[1]; pz = z_hi[2]; }
        else if (t == 10) { px = spec[0]; py = spec[1]; pz = spec[2]; }
        else if (t == 21) { px = spec[3]; py = spec[4]; pz = spec[5]; }
        else {
            int i = (t < 10) ? t : (t < 21 ? t - 11 : t - 22);
            float fi = (float)i;
            float ang = 0.62831853071795864769f * fi + ph;
            float mlt = 1.f + pci + pcs * fi;
            px = amp * cosf(ang) * mlt;
            py = amp * sinf(ang) * mlt;
            pz = (slp * fi + off) * mlt;
        }
        if (tk == 0) {
            PosT[t*3] = px; PosT[t*3+1] = py; PosT[t*3+2] = pz;
            PW[t] = make_float4(px * ln1_w[2], py * ln1_w[3], pz * ln1_w[4], 0.f);
        }
        float x0 = tok_emb[tk * 2], x1 = tok_emb[tk * 2 + 1];
        float ssum = x0*x0 + x1*x1 + px*px + py*py + pz*pz;
        float rn = rsqrtf(ssum * 0.2f + 1e-5f);
        float h0 = x0 * rn * ln1_w[0], h1 = x1 * rn * ln1_w[1];
        float h2 = px * rn * ln1_w[2], h3 = py * rn * ln1_w[3], h4 = pz * rn * ln1_w[4];
        float q0 = q_w[0]  * h2 + q_w[1]  * h3 + q_w[2]  * h4;
        float q1 = q_w[3]  * h2 + q_w[4]  * h3 + q_w[5]  * h4;
        float q2 = q_w[6]  * h2 + q_w[7]  * h3 + q_w[8]  * h4;
        float q3 = q_w[9]  * h2 + q_w[10] * h3 + q_w[11] * h4;
        float q4 = q_w[12] * h2 + q_w[13] * h3 + q_w[14] * h4;
        float r0 = q0 * cph - q1 * sph, r1 = q0 * sph + q1 * cph;
        float r2c = q2 * cph - q3 * sph, r3 = q2 * sph + q3 * cph;
        float c0 = (r0*q_w[0] + r1*q_w[3] + r2c*q_w[6] + r3*q_w[9]  + q4*q_w[12]) * cscale;
        float c1 = (r0*q_w[1] + r1*q_w[4] + r2c*q_w[7] + r3*q_w[10] + q4*q_w[13]) * cscale;
        float c2 = (r0*q_w[2] + r1*q_w[5] + r2c*q_w[8] + r3*q_w[11] + q4*q_w[14]) * cscale;
        C3[e] = make_float4(c0, c1, c2, 0.f);
        Rt[e] = make_float4(rn, h0, h1, 0.f);
    }
    if (tid < 28) TE[tid] = tok_emb[tid];
    if (tid < 70) { // WsT[v][d] = sum_c head_w[c*5+d] * tok_emb[v*2+c]
        int v = tid / 5, d = tid - v * 5;
        WsT[v * 8 + d] = head_w[d] * tok_emb[v * 2] + head_w[5 + d] * tok_emb[v * 2 + 1];
    }
    if (tid < 10) {
        int j = tid >> 1, c = tid & 1;
        float acc = 0.f;
        for (int i = 0; i < 5; ++i) {
            float m5 = out_A[i*2] * out_B[j] + out_A[i*2+1] * out_B[5 + j];
            acc += m5 * v_w[i*2 + c];
        }
        PMs[tid] = acc;
    }
    if (tid < 5)  { ln2s[tid] = ln2_w[tid]; lnfs[tid] = lnf_w[tid]; fc2bs[tid] = fc2_b[tid]; }
    if (tid < 10) { fc1ws[tid] = fc1_w[tid]; fc2ws[tid] = fc2_w[tid]; }
    if (tid < 2)  { fc1bs[tid] = fc1_b[tid]; }

    __syncthreads();

    // ---- phase 1: fused balanced pair (t1=p, t2=33-p) ----
    if (tid < 17 * ROWS) {
        int p = tid / ROWS;        // 0..16
        int rr = tid - p * ROWS;   // 0..29
        int t1 = p, t2 = 33 - p;
        const int* tRow = &toksT[rr];
        int tok1 = tRow[t1 * TTS];
        int tok2 = tRow[t2 * TTS];
        float4 c31 = C3[t1 * NTOK + tok1];
        float4 c32 = C3[t2 * NTOK + tok2];
        float l1 = 0.f, a10 = 0.f, a11 = 0.f;
        float l2 = 0.f, a20 = 0.f, a21 = 0.f;

        // region A: s = 0..p — one gather feeds BOTH t1 and t2 chains
#pragma unroll 2
        for (int s = 0; s <= p; ++s) {
            int tok = tRow[s * TTS];
            float4 R = Rt[s * NTOK + tok];
            float4 pw = PW[s];
            float d1 = fmaf(c31.x, pw.x, fmaf(c31.y, pw.y, c31.z * pw.z));
            float d2 = fmaf(c32.x, pw.x, fmaf(c32.y, pw.y, c32.z * pw.z));
            float p1 = __builtin_amdgcn_exp2f(d1 * R.x);
            float p2 = __builtin_amdgcn_exp2f(d2 * R.x);
            l1 += p1; a10 = fmaf(p1, R.y, a10); a11 = fmaf(p1, R.z, a11);
            l2 += p2; a20 = fmaf(p2, R.y, a20); a21 = fmaf(p2, R.z, a21);
        }
        // region B: s = p+1..33-p — t2 only
#pragma unroll 4
        for (int s = p + 1; s <= t2; ++s) {
            int tok = tRow[s * TTS];
            float4 R = Rt[s * NTOK + tok];
            float4 pw = PW[s];
            float d2 = fmaf(c32.x, pw.x, fmaf(c32.y, pw.y, c32.z * pw.z));
            float p2 = __builtin_amdgcn_exp2f(d2 * R.x);
            l2 += p2; a20 = fmaf(p2, R.y, a20); a21 = fmaf(p2, R.z, a21);
        }
        float il1 = __builtin_amdgcn_rcpf(l1);
        float il2 = __builtin_amdgcn_rcpf(l2);
        Av[t1 * AVS + rr] = make_float2(a10 * il1, a11 * il1);
        Av[t2 * AVS + rr] = make_float2(a20 * il2, a21 * il2);
    }

    __syncthreads();

    // ---- phase 2: residual + FFN + final RMS + logits ----
    float zA[5], zB[5];
    int linA = elemBase + tid;
    int linB = elemBase + tid + BLK;
    bool va = (linA < N);
    bool vb = (tid + BLK < NEL) && (linB < N);

    auto prep = [&](int e2, float* z) {
        int rr = e2 / T_SEQ;
        int t = e2 - rr * T_SEQ;
        int tok = toksT[t * TTS + rr];
        float2 a = Av[t * AVS + rr];
        float xv0 = TE[tok * 2], xv1 = TE[tok * 2 + 1];
        float xv2 = PosT[t*3], xv3 = PosT[t*3+1], xv4 = PosT[t*3+2];

        float y[5];
#pragma unroll
        for (int j = 0; j < 5; ++j)
            y[j] = (j == 0 ? xv0 : j == 1 ? xv1 : j == 2 ? xv2 : j == 3 ? xv3 : xv4)
                 + PMs[j*2] * a.x + PMs[j*2+1] * a.y;

        float s2 = y[0]*y[0] + y[1]*y[1] + y[2]*y[2] + y[3]*y[3] + y[4]*y[4];
        float r2 = rsqrtf(s2 * 0.2f + 1e-5f);
        float hh[5];
#pragma unroll
        for (int j = 0; j < 5; ++j) hh[j] = y[j] * r2 * ln2s[j];

        float u0 = fc1bs[0], u1 = fc1bs[1];
#pragma unroll
        for (int j = 0; j < 5; ++j) { u0 += hh[j] * fc1ws[j]; u1 += hh[j] * fc1ws[5 + j]; }
        float g0 = 0.5f * u0 * (1.f + erff(u0 * 0.70710678118654752f));
        float g1v = 0.5f * u1 * (1.f + erff(u1 * 0.70710678118654752f));

        float y2[5]; float s3 = 0.f;
#pragma unroll
        for (int j = 0; j < 5; ++j) {
            y2[j] = y[j] + g0 * fc2ws[j * 2] + g1v * fc2ws[j * 2 + 1] + fc2bs[j];
            s3 += y2[j] * y2[j];
        }
        float r3 = rsqrtf(s3 * 0.2f + 1e-5f);
#pragma unroll
        for (int j = 0; j < 5; ++j) z[j] = y2[j] * r3 * lnfs[j];
    };

    if (va) prep(tid, zA);
    if (vb) prep(tid + BLK, zB);

    float2* opA = (float2*)(out + (size_t)linA * 14);
    float2* opB = (float2*)(out + (size_t)linB * 14);
#pragma unroll
    for (int v = 0; v < 7; ++v) {
        float4 w0 = *(const float4*)&WsT[(2*v) * 8];
        float  w4 = WsT[(2*v) * 8 + 4];
        float4 u0 = *(const float4*)&WsT[(2*v+1) * 8];
        float  u4 = WsT[(2*v+1) * 8 + 4];
        if (va) {
            float rA = zA[0]*w0.x + zA[1]*w0.y + zA[2]*w0.z + zA[3]*w0.w + zA[4]*w4;
            float rB = zA[0]*u0.x + zA[1]*u0.y + zA[2]*u0.z + zA[3]*u0.w + zA[4]*u4;
            opA[v] = make_float2(rA, rB);
        }
        if (vb) {
            float rA = zB[0]*w0.x + zB[1]*w0.y + zB[2]*w0.z + zB[3]*w0.w + zB[4]*w4;
            float rB = zB[0]*u0.x + zB[1]*u0.y + zB[2]*u0.z + zB[3]*u0.w + zB[4]*u4;
            opB[v] = make_float2(rA, rB);
        }
    }
}

extern "C" void kernel_launch(void* const* d_in, const int* in_sizes, int n_in,
                              void* d_out, int out_size, void* d_ws, size_t ws_size,
                              hipStream_t stream) {
    const int N = in_sizes[0]; // B*T
    const int grid = (N + NEL - 1) / NEL;
    micro_fused_kernel<<<grid, BLK, 0, stream>>>(
        (const int*)d_in[0],
        (const float*)d_in[1], (const float*)d_in[2], (const float*)d_in[3],
        (const float*)d_in[4], (const float*)d_in[5], (const float*)d_in[6],
        (const float*)d_in[7], (const float*)d_in[8], (const float*)d_in[9],
        (const float*)d_in[10], (const float*)d_in[11], (const float*)d_in[12],
        (const float*)d_in[13], (const float*)d_in[14], (const float*)d_in[15],
        (const float*)d_in[16], (const float*)d_in[17], (const float*)d_in[18],
        (const float*)d_in[19], (const float*)d_in[20], (const float*)d_in[21],
        (const float*)d_in[22],
        (float*)d_out, N);
}